// Round 5
// baseline (1886.438 us; speedup 1.0000x reference)
//
#include <hip/hip_runtime.h>
#include <hip/hip_bf16.h>
#include <cfloat>
#include <cstdint>

// ---------------------------------------------------------------------------
// RPN pipeline (B=1): conv3d(256->512,3x3x3,SAME)+ReLU -> heads -> proposals
// Shapes: base_feat (1,256,16,32,32), H=W=32, T=16
// Outputs: rois (1,128,7), rois16 (1,128,5), 4 scalar zeros -> 1540 floats
// ---------------------------------------------------------------------------

#define T_DIM 16
#define H_DIM 32
#define W_DIM 32
#define NVOX  (T_DIM*H_DIM*W_DIM)   // 16384
#define HW    (H_DIM*W_DIM)         // 1024
#define CIN   256
#define COUT  512
#define PRE_NMS 1000
#define POST_NMS 128
#define NMS_TH 0.7f

// anchor tables: ratios (0.5,1.0,2.0) -> (ws,hs) = (23,12),(16,16),(11,22); scales 4,8,16
__constant__ float c_ws[3] = {23.f, 16.f, 11.f};
__constant__ float c_hs[3] = {12.f, 16.f, 22.f};
__constant__ float c_sc[3] = {4.f, 8.f, 16.f};
__constant__ float c_depth[3] = {16.f, 8.f, 4.f};

// ---------------------------------------------------------------------------
// Weight transpose: Wt[tap][c][o] = W[o][c][tap]
__global__ void k_transpose_w(const float* __restrict__ W, float* __restrict__ Wt) {
    int i = blockIdx.x * 256 + threadIdx.x;   // over 27*256*512 = 3538944
    int o = i & 511;
    int c = (i >> 9) & 255;
    int tap = i >> 17;
    Wt[i] = W[(o * 256 + c) * 27 + tap];
}

// Wcomb[c][o'] : o'<54 = W_cls[o'][c]; 54..215 = W_bbox[o'-54][c]; 216..255 = 0
__global__ void k_build_wcomb(const float* __restrict__ Wcls, const float* __restrict__ Wbb,
                              float* __restrict__ Wc) {
    int i = blockIdx.x * 256 + threadIdx.x;   // over 512*256
    int o = i & 255;
    int c = i >> 8;
    float v = 0.f;
    if (o < 54) v = Wcls[o * 512 + c];
    else if (o < 216) v = Wbb[(o - 54) * 512 + c];
    Wc[i] = v;
}

// ---------------------------------------------------------------------------
// conv3d as implicit GEMM: O[o][v] = relu(bias[o] + sum_{tap,c} Wt[tap][c][o]*I[c][shift(v,tap)])
// Round-5 structure: 512 threads, 128(o)x128(v) tile, per-thread 4x8 acc,
// BK=32, DOUBLE-BUFFERED LDS (one barrier per stage, 216 total), register
// prefetch with EXPLICIT SCALARS ONLY (round-3 lesson: arrays captured by
// reference spilled to scratch). Split-4 col layout -> 0 bank conflicts
// (measured rounds 3-4); A fragment read is a 4-address broadcast (free).
// 16 waves/CU (4/SIMD) vs round-4's 8 (2/SIMD): barrier/latency hiding.

// per-tap shift/bounds for the 4 staged B columns (t0,h0,w0 shared: scol%4==0)
#define CONV_COMPUTE_TAP(TAP) {                                               \
    int kt_ = (TAP) / 9 - 1, kh_ = ((TAP) / 3) % 3 - 1, kw_ = (TAP) % 3 - 1;  \
    int tt_ = t0 + kt_, hh_ = h0 + kh_;                                       \
    int vth_ = ((unsigned)tt_ < 16u) && ((unsigned)hh_ < 32u);                \
    int wb_ = w0 + kw_;                                                       \
    off0 = (tt_ << 10) + (hh_ << 5) + wb_;                                    \
    off1 = off0 + 1; off2 = off0 + 2; off3 = off0 + 3;                        \
    val0 = vth_ && ((unsigned)wb_ < 32u);                                     \
    val1 = vth_ && ((unsigned)(wb_ + 1) < 32u);                               \
    val2 = vth_ && ((unsigned)(wb_ + 2) < 32u);                               \
    val3 = vth_ && ((unsigned)(wb_ + 3) < 32u);                               \
}

// prefetch one BK=32 stage into registers (each thread: 2 A-rows, 2 B-rows)
#define CONV_LOAD(TAP, CK) {                                                  \
    const float* wp_ = Wt + ((size_t)((TAP) * 256 + (CK) + srow) << 9) + o0 + scol; \
    pa0 = *(const float4*)(wp_);                                              \
    pa1 = *(const float4*)(wp_ + (16 << 9));                                  \
    const float* ip_ = I + ((size_t)((CK) + srow) << 14);                     \
    pb0 = make_float4(val0 ? ip_[off0] : 0.f, val1 ? ip_[off1] : 0.f,         \
                      val2 ? ip_[off2] : 0.f, val3 ? ip_[off3] : 0.f);        \
    ip_ += (size_t)16 << 14;                                                  \
    pb1 = make_float4(val0 ? ip_[off0] : 0.f, val1 ? ip_[off1] : 0.f,         \
                      val2 ? ip_[off2] : 0.f, val3 ? ip_[off3] : 0.f);        \
}

// one pipeline stage against compile-time buffer BUF; single barrier
#define CONV_STAGE(S, BUF) {                                                  \
    *(float4*)(&As[BUF][srow][scol])      = pa0;                              \
    *(float4*)(&As[BUF][srow + 16][scol]) = pa1;                              \
    *(float4*)(&Bs[BUF][srow][scol])      = pb0;                              \
    *(float4*)(&Bs[BUF][srow + 16][scol]) = pb1;                              \
    __syncthreads();                                                          \
    {                                                                         \
        int s1_ = (S) + 1;                                                    \
        if (s1_ < 216) {                                                      \
            int tap1_ = s1_ >> 3, ck1_ = (s1_ & 7) << 5;                      \
            if ((s1_ & 7) == 0) CONV_COMPUTE_TAP(tap1_);                      \
            CONV_LOAD(tap1_, ck1_);                                           \
        }                                                                     \
    }                                                                         \
    _Pragma("unroll 8")                                                       \
    for (int k = 0; k < 32; ++k) {                                            \
        float a[4], b[8];                                                     \
        *(float4*)(a)     = *(const float4*)(&As[BUF][k][ry4]);               \
        *(float4*)(b)     = *(const float4*)(&Bs[BUF][k][tx4]);               \
        *(float4*)(b + 4) = *(const float4*)(&Bs[BUF][k][64 + tx4]);          \
        _Pragma("unroll")                                                     \
        for (int i = 0; i < 4; i++)                                           \
            _Pragma("unroll")                                                 \
            for (int j = 0; j < 8; j++)                                       \
                acc[i][j] = fmaf(a[i], b[j], acc[i][j]);                      \
    }                                                                         \
}

__global__ __launch_bounds__(512) void k_conv3d(const float* __restrict__ I,
                                                const float* __restrict__ Wt,
                                                const float* __restrict__ bias,
                                                float* __restrict__ O) {
    __shared__ float As[2][32][128];   // 32 KB
    __shared__ float Bs[2][32][128];   // 32 KB
    const int tid = threadIdx.x;
    const int o0 = blockIdx.y * 128;
    const int v0 = blockIdx.x * 128;
    const int ry4 = (tid >> 4) * 4;    // o-row group: 4 rows ry4..ry4+3
    const int tx4 = (tid & 15) * 4;    // v-col group: cols {tx4..+3, 64+tx4..+3}

    float acc[4][8];
#pragma unroll
    for (int i = 0; i < 4; i++)
#pragma unroll
        for (int j = 0; j < 8; j++) acc[i][j] = 0.f;

    // staging assignment: lane covers rows {srow, srow+16}, cols scol..scol+3
    const int srow = tid >> 5;          // 0..15
    const int scol = (tid & 31) * 4;    // 0..124

    // voxel decompose for staged columns (shared t/h; w0..w0+3 within a row)
    const int vbase = v0 + scol;
    const int t0 = vbase >> 10, h0 = (vbase >> 5) & 31, w0 = vbase & 31;

    int off0, off1, off2, off3;
    int val0, val1, val2, val3;
    float4 pa0, pa1, pb0, pb1;

    CONV_COMPUTE_TAP(0);
    CONV_LOAD(0, 0);

    for (int s = 0; s < 216; s += 2) {          // 27 taps * 8 ck-steps
        CONV_STAGE(s, 0);
        CONV_STAGE(s + 1, 1);
    }

    // epilogue: bias + relu
#pragma unroll
    for (int i = 0; i < 4; i++) {
        int o = o0 + ry4 + i;
        float bo = bias[o];
        float lo4[4], hi4[4];
#pragma unroll
        for (int j = 0; j < 4; j++) lo4[j] = fmaxf(acc[i][j] + bo, 0.f);
#pragma unroll
        for (int j = 0; j < 4; j++) hi4[j] = fmaxf(acc[i][4 + j] + bo, 0.f);
        float* dst = O + (size_t)o * NVOX + v0;
        *(float4*)(dst + tx4)      = *(const float4*)(lo4);
        *(float4*)(dst + 64 + tx4) = *(const float4*)(hi4);
    }
}

// ---------------------------------------------------------------------------
// logits3 GEMM: L[o][v] = sum_c Wc[c][o] * conv1[c][v], M=256 (padded), K=512, N=16384
// split-4 fragment layout (conflict-free LDS)
__global__ __launch_bounds__(256) void k_gemm_logits3(const float* __restrict__ conv1,
                                                      const float* __restrict__ Wc,
                                                      float* __restrict__ L) {
    __shared__ float As[16][128];
    __shared__ float Bs[16][128];
    const int tid = threadIdx.x;
    const int o0 = blockIdx.y * 128;
    const int v0 = blockIdx.x * 128;
    const int ty = tid >> 4, tx = tid & 15;

    float acc[8][8];
#pragma unroll
    for (int i = 0; i < 8; i++)
#pragma unroll
        for (int j = 0; j < 8; j++) acc[i][j] = 0.f;

    for (int ck = 0; ck < 512; ck += 16) {
        __syncthreads();
#pragma unroll
        for (int r = 0; r < 2; ++r) {
            int f = tid + r * 256;
            int c_l = f >> 5, o4 = (f & 31) << 2;
            *(float4*)(&As[c_l][o4]) = *(const float4*)(Wc + ((size_t)(ck + c_l) << 8) + o0 + o4);
        }
#pragma unroll
        for (int r = 0; r < 2; ++r) {
            int f = tid + r * 256;
            int c_l = f >> 5, v4 = (f & 31) << 2;
            *(float4*)(&Bs[c_l][v4]) = *(const float4*)(conv1 + ((size_t)(ck + c_l) << 14) + v0 + v4);
        }
        __syncthreads();
#pragma unroll
        for (int k = 0; k < 16; ++k) {
            float a[8], b[8];
            *(float4*)(a)     = *(const float4*)(&As[k][ty * 4]);
            *(float4*)(a + 4) = *(const float4*)(&As[k][64 + ty * 4]);
            *(float4*)(b)     = *(const float4*)(&Bs[k][tx * 4]);
            *(float4*)(b + 4) = *(const float4*)(&Bs[k][64 + tx * 4]);
#pragma unroll
            for (int i = 0; i < 8; i++)
#pragma unroll
                for (int j = 0; j < 8; j++)
                    acc[i][j] = fmaf(a[i], b[j], acc[i][j]);
        }
    }
#pragma unroll
    for (int i = 0; i < 8; i++) {
        int orow = (i < 4) ? (ty * 4 + i) : (64 + ty * 4 + (i - 4));
        float* dst = L + (size_t)(o0 + orow) * NVOX + v0;
        *(float4*)(dst + tx * 4)      = *(const float4*)(&acc[i][0]);
        *(float4*)(dst + 64 + tx * 4) = *(const float4*)(&acc[i][4]);
    }
}

// ---------------------------------------------------------------------------
// sc3[hw*27+a] = mean_t softmax-fg of (L[a]+b[a], L[27+a]+b[27+a])
__global__ void k_sc3(const float* __restrict__ L, const float* __restrict__ b_cls,
                      float* __restrict__ sc3) {
    int i = blockIdx.x * 256 + threadIdx.x;   // 27648
    if (i >= 27 * HW) return;
    int a = i >> 10, hw = i & 1023;
    float b0 = b_cls[a], b1 = b_cls[27 + a];
    const float* L0 = L + (size_t)a * NVOX + hw;
    const float* L1 = L + (size_t)(27 + a) * NVOX + hw;
    float s = 0.f;
    for (int t = 0; t < T_DIM; t++) {
        float x0 = L0[t * HW] + b0, x1 = L1[t * HW] + b1;
        float m = fmaxf(x0, x1);
        float e0 = expf(x0 - m), e1 = expf(x1 - m);
        s += e1 / (e0 + e1);
    }
    sc3[hw * 27 + a] = s * (1.f / 16.f);
}

// dl3[(hw*27+a)*6+d] = mean_t L[54+a*6+d] + b_bbox[a*6+d]
__global__ void k_dl3(const float* __restrict__ L, const float* __restrict__ b_bbox,
                      float* __restrict__ dl3) {
    int i = blockIdx.x * 256 + threadIdx.x;   // 165888
    if (i >= 162 * HW) return;
    int ch = i >> 10, hw = i & 1023;
    const float* Lr = L + (size_t)(54 + ch) * NVOX + hw;
    float s = 0.f;
    for (int t = 0; t < T_DIM; t++) s += Lr[t * HW];
    s = s * (1.f / 16.f) + b_bbox[ch];
    int a = ch / 6, d = ch - a * 6;
    dl3[((size_t)hw * 27 + a) * 6 + d] = s;
}

// feat2[c*1024+hw] = mean_t conv1[c][t*1024+hw]
__global__ void k_feat2(const float* __restrict__ conv1, float* __restrict__ feat2) {
    int i = blockIdx.x * 256 + threadIdx.x;   // 524288
    int c = i >> 10, hw = i & 1023;
    const float* src = conv1 + (size_t)c * NVOX + hw;
    float s = 0.f;
    for (int t = 0; t < T_DIM; t++) s += src[t * HW];
    feat2[i] = s * (1.f / 16.f);
}

// L2[o*1024+hw] (o<54): rows 0..17 = W_cls16, 18..53 = W_bbox16 (no bias)
__global__ void k_gemm2d(const float* __restrict__ feat2, const float* __restrict__ Wcls16,
                         const float* __restrict__ Wbb16, float* __restrict__ L2) {
    int g = blockIdx.x * 256 + threadIdx.x;   // 55296
    int o = g >> 10, hw = g & 1023;
    const float* wrow = (o < 18) ? (Wcls16 + (size_t)o * 512) : (Wbb16 + (size_t)(o - 18) * 512);
    float s = 0.f;
    for (int c = 0; c < 512; c++) s = fmaf(wrow[c], feat2[(size_t)c * HW + hw], s);
    L2[(size_t)o * HW + hw] = s;
}

__global__ void k_sc2(const float* __restrict__ L2, const float* __restrict__ b_cls16,
                      float* __restrict__ sc2) {
    int i = blockIdx.x * 256 + threadIdx.x;   // 9216
    if (i >= 9 * HW) return;
    int a = i >> 10, hw = i & 1023;
    float x0 = L2[(size_t)a * HW + hw] + b_cls16[a];
    float x1 = L2[(size_t)(9 + a) * HW + hw] + b_cls16[9 + a];
    float m = fmaxf(x0, x1);
    float e0 = expf(x0 - m), e1 = expf(x1 - m);
    sc2[hw * 9 + a] = e1 / (e0 + e1);
}

__global__ void k_dl2(const float* __restrict__ L2, const float* __restrict__ b_bbox16,
                      float* __restrict__ dl2) {
    int i = blockIdx.x * 256 + threadIdx.x;   // 36864
    if (i >= 36 * HW) return;
    int ch = i >> 10, hw = i & 1023;
    float v = L2[(size_t)(18 + ch) * HW + hw] + b_bbox16[ch];
    int a = ch >> 2, d = ch & 3;
    dl2[((size_t)hw * 9 + a) * 4 + d] = v;
}

// ---------------------------------------------------------------------------
// monotone map: larger float -> larger unsigned
__device__ __forceinline__ unsigned mapf(float f) {
    unsigned u = __float_as_uint(f);
    return (u & 0x80000000u) ? ~u : (u | 0x80000000u);
}

// proposal: radix-select top-1000 -> bitonic sort -> decode+clip -> bitmask NMS
// blockIdx.x = 0: 3D branch (A=27, nd=3), 1: 2D branch (A=9, nd=2)
__global__ __launch_bounds__(1024) void k_proposal(const float* __restrict__ im_info,
                                                   const float* __restrict__ sc3,
                                                   const float* __restrict__ dl3,
                                                   const float* __restrict__ sc2,
                                                   const float* __restrict__ dl2,
                                                   float* __restrict__ out) {
    const int branch = blockIdx.x;
    const int tid = threadIdx.x;
    const int A = (branch == 0) ? 27 : 9;
    const int nd = (branch == 0) ? 3 : 2;
    const float* scores = (branch == 0) ? sc3 : sc2;
    const float* deltas = (branch == 0) ? dl3 : dl2;
    const int K = PRE_NMS;
    const int ept = A;                 // elements per thread; S = 1024*ept
    const int base = tid * ept;

    __shared__ unsigned hist[256];
    __shared__ unsigned long long keys[1024];
    __shared__ float bx[PRE_NMS][6];
    __shared__ int keep[POST_NMS];
    __shared__ unsigned wsum[16];
    __shared__ unsigned long long alive[16];
    __shared__ int sh_b, sh_next, bcast;

    // ================= radix-select: find mapped value of K-th largest ======
    unsigned prefix = 0;
    int rank = K;                      // rank of target within current subset
    for (int shift = 24; shift >= 0; shift -= 8) {
        if (tid < 256) hist[tid] = 0;
        __syncthreads();
        const unsigned mask_hi = (shift == 24) ? 0u : (0xFFFFFFFFu << (shift + 8));
        for (int j = 0; j < ept; j++) {
            unsigned m = mapf(scores[base + j]);
            if ((m & mask_hi) == prefix)
                atomicAdd(&hist[(m >> shift) & 255], 1u);
        }
        __syncthreads();
        // suffix sums in place: hist[b] := sum_{j>=b} hist[j]
        for (int d = 1; d < 256; d <<= 1) {
            unsigned add = 0;
            if (tid < 256 && tid + d < 256) add = hist[tid + d];
            __syncthreads();
            if (tid < 256) hist[tid] += add;
            __syncthreads();
        }
        // b = max { b : suf[b] >= rank }  (unique winner writes)
        if (tid < 256) {
            bool win = (hist[tid] >= (unsigned)rank) &&
                       (tid == 255 || hist[tid + 1] < (unsigned)rank);
            if (win) { sh_b = tid; sh_next = (tid == 255) ? 0 : (int)hist[tid + 1]; }
        }
        __syncthreads();
        prefix |= (unsigned)sh_b << shift;
        rank -= sh_next;
        __syncthreads();
    }
    const unsigned tau = prefix;       // mapped K-th largest; rank = #eq needed

    // ================= compaction: >tau all, ==tau smallest-index 'rank' ====
    int gt_c = 0, eq_c = 0;
    for (int j = 0; j < ept; j++) {
        unsigned m = mapf(scores[base + j]);
        gt_c += (m > tau);
        eq_c += (m == tau);
    }
    unsigned cnt = ((unsigned)gt_c << 16) | (unsigned)eq_c;
    // block exclusive scan (index order)
    const int lane = tid & 63, wid = tid >> 6;
    unsigned x = cnt;
    for (int d = 1; d < 64; d <<= 1) {
        unsigned y = __shfl_up(x, d);
        if (lane >= d) x += y;
    }
    if (lane == 63) wsum[wid] = x;
    __syncthreads();
    if (wid == 0) {
        unsigned w = (lane < 16) ? wsum[lane] : 0;
        for (int d = 1; d < 16; d <<= 1) {
            unsigned y = __shfl_up(w, d);
            if (lane >= d) w += y;
        }
        if (lane < 16) wsum[lane] = w;
    }
    __syncthreads();
    unsigned excl = x - cnt + (wid ? wsum[wid - 1] : 0);
    const int c1 = (int)(wsum[15] >> 16);          // total count > tau (< K)
    int gi = (int)(excl >> 16);
    int ei = (int)(excl & 0xFFFFu);
    for (int j = 0; j < ept; j++) {
        int idx = base + j;
        unsigned m = mapf(scores[idx]);
        unsigned long long key = ((unsigned long long)m << 32) |
                                 (unsigned)(0xFFFFFFFFu - (unsigned)idx);
        if (m > tau) {
            keys[gi++] = key;
        } else if (m == tau) {
            if (c1 + ei < K) keys[c1 + ei] = key;
            ei++;
        }
    }
    if (tid < 1024 - K) keys[K + tid] = 0;         // pad tail
    __syncthreads();

    // ================= bitonic sort 1024 u64 keys, descending ===============
    for (int k = 2; k <= 1024; k <<= 1) {
        for (int j = k >> 1; j > 0; j >>= 1) {
            int ixj = tid ^ j;
            if (ixj > tid) {
                unsigned long long a = keys[tid], b = keys[ixj];
                bool sw = ((tid & k) == 0) ? (a < b) : (a > b);
                if (sw) { keys[tid] = b; keys[ixj] = a; }
            }
            __syncthreads();
        }
    }

    // ================= decode + clip ========================================
    const float imh = im_info[0], imw = im_info[1];
    if (tid < K) {
        int n = (int)(0xFFFFFFFFu - (unsigned)(keys[tid] & 0xFFFFFFFFull));
        int cell = n / A, a = n - cell * A;
        int hc = cell >> 5, wc = cell & 31;
        int a2 = (branch == 0) ? (a % 9) : a;
        int ri = a2 / 3, si = a2 % 3;
        float w = c_ws[ri] * c_sc[si], h = c_hs[ri] * c_sc[si];
        float lo[3], hi[3], mx[3];
        lo[0] = 7.5f - (w - 1.f) * 0.5f + 16.f * wc;
        hi[0] = 7.5f + (w - 1.f) * 0.5f + 16.f * wc;
        mx[0] = imw - 1.f;
        lo[1] = 7.5f - (h - 1.f) * 0.5f + 16.f * hc;
        hi[1] = 7.5f + (h - 1.f) * 0.5f + 16.f * hc;
        mx[1] = imh - 1.f;
        if (branch == 0) { lo[2] = 0.f; hi[2] = c_depth[a / 9] - 1.f; mx[2] = (float)(T_DIM - 1); }
        const float* dp = deltas + (size_t)n * (2 * nd);
        for (int d = 0; d < nd; d++) {
            float size = hi[d] - lo[d] + 1.f;
            float ctr = lo[d] + 0.5f * (size - 1.f);
            float pctr = dp[d] * size + ctr;
            float psize = expf(dp[nd + d]) * size;
            float pl = pctr - 0.5f * (psize - 1.f);
            float ph = pctr + 0.5f * (psize - 1.f);
            bx[tid][d]      = fminf(fmaxf(pl, 0.f), mx[d]);
            bx[tid][nd + d] = fminf(fmaxf(ph, 0.f), mx[d]);
        }
    }
    // init alive bitmask (bits 0..K-1 set)
    if (tid < 16) alive[tid] = (tid < 15) ? ~0ull : ((1ull << (K - 15 * 64)) - 1);
    __syncthreads();

    // ================= NMS (bitmask) ========================================
    float myb[6]; float myvol = 1.f;
    if (tid < K) {
        for (int d = 0; d < 6; d++) myb[d] = bx[tid][d];
        for (int d = 0; d < nd; d++) myvol *= (myb[nd + d] - myb[d] + 1.f);
    }
    for (int i = 0; i < POST_NMS; ++i) {
        if (tid < 64) {
            unsigned long long wv = (tid < 16) ? alive[tid] : 0ull;
            int cand = wv ? (tid * 64 + __ffsll(wv) - 1) : 0x7fffffff;
#pragma unroll
            for (int off = 32; off; off >>= 1)
                cand = min(cand, __shfl_xor(cand, off));
            if (tid == 0) {
                int m = (cand == 0x7fffffff) ? 0 : cand;
                bcast = m; keep[i] = m;
            }
        }
        __syncthreads();
        int sel = bcast;
        bool s = false;
        if (tid < K) {
            float inter = 1.f, selvol = 1.f;
            for (int d = 0; d < nd; d++) {
                float slo = bx[sel][d], shi = bx[sel][nd + d];
                float l = fmaxf(slo, myb[d]);
                float hh = fminf(shi, myb[nd + d]);
                inter *= fmaxf(hh - l + 1.f, 0.f);
                selvol *= (shi - slo + 1.f);
            }
            float iou = inter / (selvol + myvol - inter);
            s = (iou > NMS_TH) || (tid == sel);
        }
        unsigned long long bal = __ballot(s);
        if (lane == 0 && bal) alive[wid] &= ~bal;
        __syncthreads();
    }

    // ================= write outputs ========================================
    if (tid < POST_NMS) {
        int k = keep[tid];
        if (branch == 0) {
            float* o = out + (size_t)tid * 7;
            o[0] = 0.f;
            for (int d = 0; d < 6; d++) o[1 + d] = bx[k][d];
        } else {
            float* o = out + 128 * 7 + (size_t)tid * 5;
            o[0] = 0.f;
            for (int d = 0; d < 4; d++) o[1 + d] = bx[k][d];
        }
    }
    if (branch == 0 && tid == 0) {
        out[1536] = 0.f; out[1537] = 0.f; out[1538] = 0.f; out[1539] = 0.f;
    }
}

// ---------------------------------------------------------------------------
extern "C" void kernel_launch(void* const* d_in, const int* in_sizes, int n_in,
                              void* d_out, int out_size, void* d_ws, size_t ws_size,
                              hipStream_t stream) {
    (void)in_sizes; (void)n_in; (void)out_size; (void)ws_size;
    const float* base_feat = (const float*)d_in[0];
    const float* im_info   = (const float*)d_in[1];
    const float* W_conv    = (const float*)d_in[4];
    const float* b_conv    = (const float*)d_in[5];
    const float* W_cls     = (const float*)d_in[6];
    const float* b_cls     = (const float*)d_in[7];
    const float* W_bbox    = (const float*)d_in[8];
    const float* b_bbox    = (const float*)d_in[9];
    const float* W_cls16   = (const float*)d_in[10];
    const float* b_cls16   = (const float*)d_in[11];
    const float* W_bbox16  = (const float*)d_in[12];
    const float* b_bbox16  = (const float*)d_in[13];
    float* out = (float*)d_out;

    // workspace layout (bytes, all 16B aligned)
    char* ws = (char*)d_ws;
    size_t off = 0;
    float* Wt     = (float*)(ws + off); off += (size_t)27 * 256 * 512 * 4;
    float* Wcomb  = (float*)(ws + off); off += (size_t)512 * 256 * 4;
    float* conv1  = (float*)(ws + off); off += (size_t)COUT * NVOX * 4;
    float* L3     = (float*)(ws + off); off += (size_t)256 * NVOX * 4;
    float* feat2  = (float*)(ws + off); off += (size_t)512 * HW * 4;
    float* L2     = (float*)(ws + off); off += (size_t)64 * HW * 4;
    float* sc3    = (float*)(ws + off); off += (size_t)27 * HW * 4;
    float* dl3    = (float*)(ws + off); off += (size_t)27 * HW * 6 * 4;
    float* sc2    = (float*)(ws + off); off += (size_t)9 * HW * 4;
    float* dl2    = (float*)(ws + off); off += (size_t)9 * HW * 4 * 4;

    k_transpose_w<<<13824, 256, 0, stream>>>(W_conv, Wt);
    k_build_wcomb<<<512, 256, 0, stream>>>(W_cls, W_bbox, Wcomb);
    {
        dim3 g(NVOX / 128, COUT / 128);
        k_conv3d<<<g, 512, 0, stream>>>(base_feat, Wt, b_conv, conv1);
    }
    {
        dim3 g(NVOX / 128, 2);
        k_gemm_logits3<<<g, 256, 0, stream>>>(conv1, Wcomb, L3);
    }
    k_sc3<<<(27 * HW + 255) / 256, 256, 0, stream>>>(L3, b_cls, sc3);
    k_dl3<<<(162 * HW + 255) / 256, 256, 0, stream>>>(L3, b_bbox, dl3);
    k_feat2<<<(512 * HW) / 256, 256, 0, stream>>>(conv1, feat2);
    k_gemm2d<<<(54 * HW) / 256, 256, 0, stream>>>(feat2, W_cls16, W_bbox16, L2);
    k_sc2<<<(9 * HW + 255) / 256, 256, 0, stream>>>(L2, b_cls16, sc2);
    k_dl2<<<(36 * HW + 255) / 256, 256, 0, stream>>>(L2, b_bbox16, dl2);
    k_proposal<<<2, 1024, 0, stream>>>(im_info, sc3, dl3, sc2, dl2, out);
}

// Round 6
// 1864.222 us; speedup vs baseline: 1.0119x; 1.0119x over previous
//
#include <hip/hip_runtime.h>
#include <hip/hip_bf16.h>
#include <cfloat>
#include <cstdint>

// ---------------------------------------------------------------------------
// RPN pipeline (B=1): conv3d(256->512,3x3x3,SAME)+ReLU -> heads -> proposals
// Shapes: base_feat (1,256,16,32,32), H=W=32, T=16
// Outputs: rois (1,128,7), rois16 (1,128,5), 4 scalar zeros -> 1540 floats
// ---------------------------------------------------------------------------

#define T_DIM 16
#define H_DIM 32
#define W_DIM 32
#define NVOX  (T_DIM*H_DIM*W_DIM)   // 16384
#define HW    (H_DIM*W_DIM)         // 1024
#define CIN   256
#define COUT  512
#define PRE_NMS 1000
#define POST_NMS 128
#define NMS_TH 0.7f

// anchor tables: ratios (0.5,1.0,2.0) -> (ws,hs) = (23,12),(16,16),(11,22); scales 4,8,16
__constant__ float c_ws[3] = {23.f, 16.f, 11.f};
__constant__ float c_hs[3] = {12.f, 16.f, 22.f};
__constant__ float c_sc[3] = {4.f, 8.f, 16.f};
__constant__ float c_depth[3] = {16.f, 8.f, 4.f};

// ---------------------------------------------------------------------------
// Weight transpose: Wt[tap][c][o] = W[o][c][tap]
__global__ void k_transpose_w(const float* __restrict__ W, float* __restrict__ Wt) {
    int i = blockIdx.x * 256 + threadIdx.x;   // over 27*256*512 = 3538944
    int o = i & 511;
    int c = (i >> 9) & 255;
    int tap = i >> 17;
    Wt[i] = W[(o * 256 + c) * 27 + tap];
}

// Wcomb[c][o'] : o'<54 = W_cls[o'][c]; 54..215 = W_bbox[o'-54][c]; 216..255 = 0
__global__ void k_build_wcomb(const float* __restrict__ Wcls, const float* __restrict__ Wbb,
                              float* __restrict__ Wc) {
    int i = blockIdx.x * 256 + threadIdx.x;   // over 512*256
    int o = i & 255;
    int c = i >> 8;
    float v = 0.f;
    if (o < 54) v = Wcls[o * 512 + c];
    else if (o < 216) v = Wbb[(o - 54) * 512 + c];
    Wc[i] = v;
}

// ---------------------------------------------------------------------------
// conv3d as implicit GEMM: O[o][v] = relu(bias[o] + sum_{tap,c} Wt[tap][c][o]*I[c][shift(v,tap)])
// Round-6 structure: 256 threads, 128x128 tile, 8x8 per thread (best
// LDS-bytes-per-FMA ratio: 16 floats / 64 FMA -> ~128 B/cyc/CU demand vs
// ~112 achievable, ceiling ~88% VALU), BK=16 DOUBLE-BUFFERED (32 KB LDS
// -> 4 blocks/CU = 4 waves/SIMD for barrier/latency hiding; one barrier
// per stage, 432 stages). Explicit scalars only (round-3 lesson: spills).
// Split-4 fragment layout: 0 bank conflicts (measured rounds 3-5).

// per-tap shift/bounds for the 4 staged B columns (t0,h0,w0 shared: scol%4==0)
#define CONV_COMPUTE_TAP(TAP) {                                               \
    int kt_ = (TAP) / 9 - 1, kh_ = ((TAP) / 3) % 3 - 1, kw_ = (TAP) % 3 - 1;  \
    int tt_ = t0 + kt_, hh_ = h0 + kh_;                                       \
    int vth_ = ((unsigned)tt_ < 16u) && ((unsigned)hh_ < 32u);                \
    int wb_ = w0 + kw_;                                                       \
    off0 = (tt_ << 10) + (hh_ << 5) + wb_;                                    \
    off1 = off0 + 1; off2 = off0 + 2; off3 = off0 + 3;                        \
    val0 = vth_ && ((unsigned)wb_ < 32u);                                     \
    val1 = vth_ && ((unsigned)(wb_ + 1) < 32u);                               \
    val2 = vth_ && ((unsigned)(wb_ + 2) < 32u);                               \
    val3 = vth_ && ((unsigned)(wb_ + 3) < 32u);                               \
}

// prefetch one BK=16 stage into registers (each thread: 2 A-rows, 2 B-rows)
#define CONV_LOAD(TAP, CK) {                                                  \
    const float* wp_ = Wt + ((size_t)((TAP) * 256 + (CK) + srow) << 9) + o0 + scol; \
    pa0 = *(const float4*)(wp_);                                              \
    pa1 = *(const float4*)(wp_ + (8 << 9));                                   \
    const float* ip_ = I + ((size_t)((CK) + srow) << 14);                     \
    pb0 = make_float4(val0 ? ip_[off0] : 0.f, val1 ? ip_[off1] : 0.f,         \
                      val2 ? ip_[off2] : 0.f, val3 ? ip_[off3] : 0.f);        \
    ip_ += (size_t)8 << 14;                                                   \
    pb1 = make_float4(val0 ? ip_[off0] : 0.f, val1 ? ip_[off1] : 0.f,         \
                      val2 ? ip_[off2] : 0.f, val3 ? ip_[off3] : 0.f);        \
}

// one pipeline stage against compile-time buffer BUF; single barrier
#define CONV_STAGE(S, BUF) {                                                  \
    *(float4*)(&As[BUF][srow][scol])     = pa0;                               \
    *(float4*)(&As[BUF][srow + 8][scol]) = pa1;                               \
    *(float4*)(&Bs[BUF][srow][scol])     = pb0;                               \
    *(float4*)(&Bs[BUF][srow + 8][scol]) = pb1;                               \
    __syncthreads();                                                          \
    {                                                                         \
        int s1_ = (S) + 1;                                                    \
        if (s1_ < 432) {                                                      \
            int tap1_ = s1_ >> 4, ck1_ = (s1_ & 15) << 4;                     \
            if ((s1_ & 15) == 0) CONV_COMPUTE_TAP(tap1_);                     \
            CONV_LOAD(tap1_, ck1_);                                           \
        }                                                                     \
    }                                                                         \
    _Pragma("unroll 8")                                                       \
    for (int k = 0; k < 16; ++k) {                                            \
        float a[8], b[8];                                                     \
        *(float4*)(a)     = *(const float4*)(&As[BUF][k][ty4]);               \
        *(float4*)(a + 4) = *(const float4*)(&As[BUF][k][64 + ty4]);          \
        *(float4*)(b)     = *(const float4*)(&Bs[BUF][k][tx4]);               \
        *(float4*)(b + 4) = *(const float4*)(&Bs[BUF][k][64 + tx4]);          \
        _Pragma("unroll")                                                     \
        for (int i = 0; i < 8; i++)                                           \
            _Pragma("unroll")                                                 \
            for (int j = 0; j < 8; j++)                                       \
                acc[i][j] = fmaf(a[i], b[j], acc[i][j]);                      \
    }                                                                         \
}

__global__ __launch_bounds__(256) void k_conv3d(const float* __restrict__ I,
                                                const float* __restrict__ Wt,
                                                const float* __restrict__ bias,
                                                float* __restrict__ O) {
    __shared__ float As[2][16][128];   // 16 KB
    __shared__ float Bs[2][16][128];   // 16 KB
    const int tid = threadIdx.x;
    const int o0 = blockIdx.y * 128;
    const int v0 = blockIdx.x * 128;
    const int ty4 = (tid >> 4) * 4;    // o-rows {ty4..+3, 64+ty4..+3}
    const int tx4 = (tid & 15) * 4;    // v-cols {tx4..+3, 64+tx4..+3}

    float acc[8][8];
#pragma unroll
    for (int i = 0; i < 8; i++)
#pragma unroll
        for (int j = 0; j < 8; j++) acc[i][j] = 0.f;

    // staging assignment: lane covers rows {srow, srow+8}, cols scol..scol+3
    const int srow = tid >> 5;          // 0..7
    const int scol = (tid & 31) * 4;    // 0..124

    // voxel decompose for staged columns (shared t/h; w0..w0+3 within a row)
    const int vbase = v0 + scol;
    const int t0 = vbase >> 10, h0 = (vbase >> 5) & 31, w0 = vbase & 31;

    int off0, off1, off2, off3;
    int val0, val1, val2, val3;
    float4 pa0, pa1, pb0, pb1;

    CONV_COMPUTE_TAP(0);
    CONV_LOAD(0, 0);

    for (int s = 0; s < 432; s += 2) {          // 27 taps * 16 ck-steps
        CONV_STAGE(s, 0);
        CONV_STAGE(s + 1, 1);
    }

    // epilogue: bias + relu, split rows/cols
#pragma unroll
    for (int i = 0; i < 8; i++) {
        int orow = (i < 4) ? (ty4 + i) : (64 + ty4 + (i - 4));
        int o = o0 + orow;
        float bo = bias[o];
        float lo4[4], hi4[4];
#pragma unroll
        for (int j = 0; j < 4; j++) lo4[j] = fmaxf(acc[i][j] + bo, 0.f);
#pragma unroll
        for (int j = 0; j < 4; j++) hi4[j] = fmaxf(acc[i][4 + j] + bo, 0.f);
        float* dst = O + (size_t)o * NVOX + v0;
        *(float4*)(dst + tx4)      = *(const float4*)(lo4);
        *(float4*)(dst + 64 + tx4) = *(const float4*)(hi4);
    }
}

// ---------------------------------------------------------------------------
// logits3 GEMM: L[o][v] = sum_c Wc[c][o] * conv1[c][v], M=256 (padded), K=512, N=16384
// split-4 fragment layout (conflict-free LDS)
__global__ __launch_bounds__(256) void k_gemm_logits3(const float* __restrict__ conv1,
                                                      const float* __restrict__ Wc,
                                                      float* __restrict__ L) {
    __shared__ float As[16][128];
    __shared__ float Bs[16][128];
    const int tid = threadIdx.x;
    const int o0 = blockIdx.y * 128;
    const int v0 = blockIdx.x * 128;
    const int ty = tid >> 4, tx = tid & 15;

    float acc[8][8];
#pragma unroll
    for (int i = 0; i < 8; i++)
#pragma unroll
        for (int j = 0; j < 8; j++) acc[i][j] = 0.f;

    for (int ck = 0; ck < 512; ck += 16) {
        __syncthreads();
#pragma unroll
        for (int r = 0; r < 2; ++r) {
            int f = tid + r * 256;
            int c_l = f >> 5, o4 = (f & 31) << 2;
            *(float4*)(&As[c_l][o4]) = *(const float4*)(Wc + ((size_t)(ck + c_l) << 8) + o0 + o4);
        }
#pragma unroll
        for (int r = 0; r < 2; ++r) {
            int f = tid + r * 256;
            int c_l = f >> 5, v4 = (f & 31) << 2;
            *(float4*)(&Bs[c_l][v4]) = *(const float4*)(conv1 + ((size_t)(ck + c_l) << 14) + v0 + v4);
        }
        __syncthreads();
#pragma unroll
        for (int k = 0; k < 16; ++k) {
            float a[8], b[8];
            *(float4*)(a)     = *(const float4*)(&As[k][ty * 4]);
            *(float4*)(a + 4) = *(const float4*)(&As[k][64 + ty * 4]);
            *(float4*)(b)     = *(const float4*)(&Bs[k][tx * 4]);
            *(float4*)(b + 4) = *(const float4*)(&Bs[k][64 + tx * 4]);
#pragma unroll
            for (int i = 0; i < 8; i++)
#pragma unroll
                for (int j = 0; j < 8; j++)
                    acc[i][j] = fmaf(a[i], b[j], acc[i][j]);
        }
    }
#pragma unroll
    for (int i = 0; i < 8; i++) {
        int orow = (i < 4) ? (ty * 4 + i) : (64 + ty * 4 + (i - 4));
        float* dst = L + (size_t)(o0 + orow) * NVOX + v0;
        *(float4*)(dst + tx * 4)      = *(const float4*)(&acc[i][0]);
        *(float4*)(dst + 64 + tx * 4) = *(const float4*)(&acc[i][4]);
    }
}

// ---------------------------------------------------------------------------
// sc3[hw*27+a] = mean_t softmax-fg of (L[a]+b[a], L[27+a]+b[27+a])
__global__ void k_sc3(const float* __restrict__ L, const float* __restrict__ b_cls,
                      float* __restrict__ sc3) {
    int i = blockIdx.x * 256 + threadIdx.x;   // 27648
    if (i >= 27 * HW) return;
    int a = i >> 10, hw = i & 1023;
    float b0 = b_cls[a], b1 = b_cls[27 + a];
    const float* L0 = L + (size_t)a * NVOX + hw;
    const float* L1 = L + (size_t)(27 + a) * NVOX + hw;
    float s = 0.f;
    for (int t = 0; t < T_DIM; t++) {
        float x0 = L0[t * HW] + b0, x1 = L1[t * HW] + b1;
        float m = fmaxf(x0, x1);
        float e0 = expf(x0 - m), e1 = expf(x1 - m);
        s += e1 / (e0 + e1);
    }
    sc3[hw * 27 + a] = s * (1.f / 16.f);
}

// dl3[(hw*27+a)*6+d] = mean_t L[54+a*6+d] + b_bbox[a*6+d]
__global__ void k_dl3(const float* __restrict__ L, const float* __restrict__ b_bbox,
                      float* __restrict__ dl3) {
    int i = blockIdx.x * 256 + threadIdx.x;   // 165888
    if (i >= 162 * HW) return;
    int ch = i >> 10, hw = i & 1023;
    const float* Lr = L + (size_t)(54 + ch) * NVOX + hw;
    float s = 0.f;
    for (int t = 0; t < T_DIM; t++) s += Lr[t * HW];
    s = s * (1.f / 16.f) + b_bbox[ch];
    int a = ch / 6, d = ch - a * 6;
    dl3[((size_t)hw * 27 + a) * 6 + d] = s;
}

// feat2[c*1024+hw] = mean_t conv1[c][t*1024+hw]
__global__ void k_feat2(const float* __restrict__ conv1, float* __restrict__ feat2) {
    int i = blockIdx.x * 256 + threadIdx.x;   // 524288
    int c = i >> 10, hw = i & 1023;
    const float* src = conv1 + (size_t)c * NVOX + hw;
    float s = 0.f;
    for (int t = 0; t < T_DIM; t++) s += src[t * HW];
    feat2[i] = s * (1.f / 16.f);
}

// L2[o*1024+hw] (o<54): rows 0..17 = W_cls16, 18..53 = W_bbox16 (no bias)
__global__ void k_gemm2d(const float* __restrict__ feat2, const float* __restrict__ Wcls16,
                         const float* __restrict__ Wbb16, float* __restrict__ L2) {
    int g = blockIdx.x * 256 + threadIdx.x;   // 55296
    int o = g >> 10, hw = g & 1023;
    const float* wrow = (o < 18) ? (Wcls16 + (size_t)o * 512) : (Wbb16 + (size_t)(o - 18) * 512);
    float s = 0.f;
    for (int c = 0; c < 512; c++) s = fmaf(wrow[c], feat2[(size_t)c * HW + hw], s);
    L2[(size_t)o * HW + hw] = s;
}

__global__ void k_sc2(const float* __restrict__ L2, const float* __restrict__ b_cls16,
                      float* __restrict__ sc2) {
    int i = blockIdx.x * 256 + threadIdx.x;   // 9216
    if (i >= 9 * HW) return;
    int a = i >> 10, hw = i & 1023;
    float x0 = L2[(size_t)a * HW + hw] + b_cls16[a];
    float x1 = L2[(size_t)(9 + a) * HW + hw] + b_cls16[9 + a];
    float m = fmaxf(x0, x1);
    float e0 = expf(x0 - m), e1 = expf(x1 - m);
    sc2[hw * 9 + a] = e1 / (e0 + e1);
}

__global__ void k_dl2(const float* __restrict__ L2, const float* __restrict__ b_bbox16,
                      float* __restrict__ dl2) {
    int i = blockIdx.x * 256 + threadIdx.x;   // 36864
    if (i >= 36 * HW) return;
    int ch = i >> 10, hw = i & 1023;
    float v = L2[(size_t)(18 + ch) * HW + hw] + b_bbox16[ch];
    int a = ch >> 2, d = ch & 3;
    dl2[((size_t)hw * 9 + a) * 4 + d] = v;
}

// ---------------------------------------------------------------------------
// monotone map: larger float -> larger unsigned
__device__ __forceinline__ unsigned mapf(float f) {
    unsigned u = __float_as_uint(f);
    return (u & 0x80000000u) ? ~u : (u | 0x80000000u);
}

// proposal: radix-select top-1000 -> bitonic sort -> decode+clip -> bitmask NMS
// blockIdx.x = 0: 3D branch (A=27, nd=3), 1: 2D branch (A=9, nd=2)
__global__ __launch_bounds__(1024) void k_proposal(const float* __restrict__ im_info,
                                                   const float* __restrict__ sc3,
                                                   const float* __restrict__ dl3,
                                                   const float* __restrict__ sc2,
                                                   const float* __restrict__ dl2,
                                                   float* __restrict__ out) {
    const int branch = blockIdx.x;
    const int tid = threadIdx.x;
    const int A = (branch == 0) ? 27 : 9;
    const int nd = (branch == 0) ? 3 : 2;
    const float* scores = (branch == 0) ? sc3 : sc2;
    const float* deltas = (branch == 0) ? dl3 : dl2;
    const int K = PRE_NMS;
    const int ept = A;                 // elements per thread; S = 1024*ept
    const int base = tid * ept;

    __shared__ unsigned hist[256];
    __shared__ unsigned long long keys[1024];
    __shared__ float bx[PRE_NMS][6];
    __shared__ int keep[POST_NMS];
    __shared__ unsigned wsum[16];
    __shared__ unsigned long long alive[16];
    __shared__ int sh_b, sh_next, bcast;

    // ================= radix-select: find mapped value of K-th largest ======
    unsigned prefix = 0;
    int rank = K;                      // rank of target within current subset
    for (int shift = 24; shift >= 0; shift -= 8) {
        if (tid < 256) hist[tid] = 0;
        __syncthreads();
        const unsigned mask_hi = (shift == 24) ? 0u : (0xFFFFFFFFu << (shift + 8));
        for (int j = 0; j < ept; j++) {
            unsigned m = mapf(scores[base + j]);
            if ((m & mask_hi) == prefix)
                atomicAdd(&hist[(m >> shift) & 255], 1u);
        }
        __syncthreads();
        // suffix sums in place: hist[b] := sum_{j>=b} hist[j]
        for (int d = 1; d < 256; d <<= 1) {
            unsigned add = 0;
            if (tid < 256 && tid + d < 256) add = hist[tid + d];
            __syncthreads();
            if (tid < 256) hist[tid] += add;
            __syncthreads();
        }
        // b = max { b : suf[b] >= rank }  (unique winner writes)
        if (tid < 256) {
            bool win = (hist[tid] >= (unsigned)rank) &&
                       (tid == 255 || hist[tid + 1] < (unsigned)rank);
            if (win) { sh_b = tid; sh_next = (tid == 255) ? 0 : (int)hist[tid + 1]; }
        }
        __syncthreads();
        prefix |= (unsigned)sh_b << shift;
        rank -= sh_next;
        __syncthreads();
    }
    const unsigned tau = prefix;       // mapped K-th largest; rank = #eq needed

    // ================= compaction: >tau all, ==tau smallest-index 'rank' ====
    int gt_c = 0, eq_c = 0;
    for (int j = 0; j < ept; j++) {
        unsigned m = mapf(scores[base + j]);
        gt_c += (m > tau);
        eq_c += (m == tau);
    }
    unsigned cnt = ((unsigned)gt_c << 16) | (unsigned)eq_c;
    // block exclusive scan (index order)
    const int lane = tid & 63, wid = tid >> 6;
    unsigned x = cnt;
    for (int d = 1; d < 64; d <<= 1) {
        unsigned y = __shfl_up(x, d);
        if (lane >= d) x += y;
    }
    if (lane == 63) wsum[wid] = x;
    __syncthreads();
    if (wid == 0) {
        unsigned w = (lane < 16) ? wsum[lane] : 0;
        for (int d = 1; d < 16; d <<= 1) {
            unsigned y = __shfl_up(w, d);
            if (lane >= d) w += y;
        }
        if (lane < 16) wsum[lane] = w;
    }
    __syncthreads();
    unsigned excl = x - cnt + (wid ? wsum[wid - 1] : 0);
    const int c1 = (int)(wsum[15] >> 16);          // total count > tau (< K)
    int gi = (int)(excl >> 16);
    int ei = (int)(excl & 0xFFFFu);
    for (int j = 0; j < ept; j++) {
        int idx = base + j;
        unsigned m = mapf(scores[idx]);
        unsigned long long key = ((unsigned long long)m << 32) |
                                 (unsigned)(0xFFFFFFFFu - (unsigned)idx);
        if (m > tau) {
            keys[gi++] = key;
        } else if (m == tau) {
            if (c1 + ei < K) keys[c1 + ei] = key;
            ei++;
        }
    }
    if (tid < 1024 - K) keys[K + tid] = 0;         // pad tail
    __syncthreads();

    // ================= bitonic sort 1024 u64 keys, descending ===============
    for (int k = 2; k <= 1024; k <<= 1) {
        for (int j = k >> 1; j > 0; j >>= 1) {
            int ixj = tid ^ j;
            if (ixj > tid) {
                unsigned long long a = keys[tid], b = keys[ixj];
                bool sw = ((tid & k) == 0) ? (a < b) : (a > b);
                if (sw) { keys[tid] = b; keys[ixj] = a; }
            }
            __syncthreads();
        }
    }

    // ================= decode + clip ========================================
    const float imh = im_info[0], imw = im_info[1];
    if (tid < K) {
        int n = (int)(0xFFFFFFFFu - (unsigned)(keys[tid] & 0xFFFFFFFFull));
        int cell = n / A, a = n - cell * A;
        int hc = cell >> 5, wc = cell & 31;
        int a2 = (branch == 0) ? (a % 9) : a;
        int ri = a2 / 3, si = a2 % 3;
        float w = c_ws[ri] * c_sc[si], h = c_hs[ri] * c_sc[si];
        float lo[3], hi[3], mx[3];
        lo[0] = 7.5f - (w - 1.f) * 0.5f + 16.f * wc;
        hi[0] = 7.5f + (w - 1.f) * 0.5f + 16.f * wc;
        mx[0] = imw - 1.f;
        lo[1] = 7.5f - (h - 1.f) * 0.5f + 16.f * hc;
        hi[1] = 7.5f + (h - 1.f) * 0.5f + 16.f * hc;
        mx[1] = imh - 1.f;
        if (branch == 0) { lo[2] = 0.f; hi[2] = c_depth[a / 9] - 1.f; mx[2] = (float)(T_DIM - 1); }
        const float* dp = deltas + (size_t)n * (2 * nd);
        for (int d = 0; d < nd; d++) {
            float size = hi[d] - lo[d] + 1.f;
            float ctr = lo[d] + 0.5f * (size - 1.f);
            float pctr = dp[d] * size + ctr;
            float psize = expf(dp[nd + d]) * size;
            float pl = pctr - 0.5f * (psize - 1.f);
            float ph = pctr + 0.5f * (psize - 1.f);
            bx[tid][d]      = fminf(fmaxf(pl, 0.f), mx[d]);
            bx[tid][nd + d] = fminf(fmaxf(ph, 0.f), mx[d]);
        }
    }
    // init alive bitmask (bits 0..K-1 set)
    if (tid < 16) alive[tid] = (tid < 15) ? ~0ull : ((1ull << (K - 15 * 64)) - 1);
    __syncthreads();

    // ================= NMS (bitmask) ========================================
    float myb[6]; float myvol = 1.f;
    if (tid < K) {
        for (int d = 0; d < 6; d++) myb[d] = bx[tid][d];
        for (int d = 0; d < nd; d++) myvol *= (myb[nd + d] - myb[d] + 1.f);
    }
    for (int i = 0; i < POST_NMS; ++i) {
        if (tid < 64) {
            unsigned long long wv = (tid < 16) ? alive[tid] : 0ull;
            int cand = wv ? (tid * 64 + __ffsll(wv) - 1) : 0x7fffffff;
#pragma unroll
            for (int off = 32; off; off >>= 1)
                cand = min(cand, __shfl_xor(cand, off));
            if (tid == 0) {
                int m = (cand == 0x7fffffff) ? 0 : cand;
                bcast = m; keep[i] = m;
            }
        }
        __syncthreads();
        int sel = bcast;
        bool s = false;
        if (tid < K) {
            float inter = 1.f, selvol = 1.f;
            for (int d = 0; d < nd; d++) {
                float slo = bx[sel][d], shi = bx[sel][nd + d];
                float l = fmaxf(slo, myb[d]);
                float hh = fminf(shi, myb[nd + d]);
                inter *= fmaxf(hh - l + 1.f, 0.f);
                selvol *= (shi - slo + 1.f);
            }
            float iou = inter / (selvol + myvol - inter);
            s = (iou > NMS_TH) || (tid == sel);
        }
        unsigned long long bal = __ballot(s);
        if (lane == 0 && bal) alive[wid] &= ~bal;
        __syncthreads();
    }

    // ================= write outputs ========================================
    if (tid < POST_NMS) {
        int k = keep[tid];
        if (branch == 0) {
            float* o = out + (size_t)tid * 7;
            o[0] = 0.f;
            for (int d = 0; d < 6; d++) o[1 + d] = bx[k][d];
        } else {
            float* o = out + 128 * 7 + (size_t)tid * 5;
            o[0] = 0.f;
            for (int d = 0; d < 4; d++) o[1 + d] = bx[k][d];
        }
    }
    if (branch == 0 && tid == 0) {
        out[1536] = 0.f; out[1537] = 0.f; out[1538] = 0.f; out[1539] = 0.f;
    }
}

// ---------------------------------------------------------------------------
extern "C" void kernel_launch(void* const* d_in, const int* in_sizes, int n_in,
                              void* d_out, int out_size, void* d_ws, size_t ws_size,
                              hipStream_t stream) {
    (void)in_sizes; (void)n_in; (void)out_size; (void)ws_size;
    const float* base_feat = (const float*)d_in[0];
    const float* im_info   = (const float*)d_in[1];
    const float* W_conv    = (const float*)d_in[4];
    const float* b_conv    = (const float*)d_in[5];
    const float* W_cls     = (const float*)d_in[6];
    const float* b_cls     = (const float*)d_in[7];
    const float* W_bbox    = (const float*)d_in[8];
    const float* b_bbox    = (const float*)d_in[9];
    const float* W_cls16   = (const float*)d_in[10];
    const float* b_cls16   = (const float*)d_in[11];
    const float* W_bbox16  = (const float*)d_in[12];
    const float* b_bbox16  = (const float*)d_in[13];
    float* out = (float*)d_out;

    // workspace layout (bytes, all 16B aligned)
    char* ws = (char*)d_ws;
    size_t off = 0;
    float* Wt     = (float*)(ws + off); off += (size_t)27 * 256 * 512 * 4;
    float* Wcomb  = (float*)(ws + off); off += (size_t)512 * 256 * 4;
    float* conv1  = (float*)(ws + off); off += (size_t)COUT * NVOX * 4;
    float* L3     = (float*)(ws + off); off += (size_t)256 * NVOX * 4;
    float* feat2  = (float*)(ws + off); off += (size_t)512 * HW * 4;
    float* L2     = (float*)(ws + off); off += (size_t)64 * HW * 4;
    float* sc3    = (float*)(ws + off); off += (size_t)27 * HW * 4;
    float* dl3    = (float*)(ws + off); off += (size_t)27 * HW * 6 * 4;
    float* sc2    = (float*)(ws + off); off += (size_t)9 * HW * 4;
    float* dl2    = (float*)(ws + off); off += (size_t)9 * HW * 4 * 4;

    k_transpose_w<<<13824, 256, 0, stream>>>(W_conv, Wt);
    k_build_wcomb<<<512, 256, 0, stream>>>(W_cls, W_bbox, Wcomb);
    {
        dim3 g(NVOX / 128, COUT / 128);
        k_conv3d<<<g, 256, 0, stream>>>(base_feat, Wt, b_conv, conv1);
    }
    {
        dim3 g(NVOX / 128, 2);
        k_gemm_logits3<<<g, 256, 0, stream>>>(conv1, Wcomb, L3);
    }
    k_sc3<<<(27 * HW + 255) / 256, 256, 0, stream>>>(L3, b_cls, sc3);
    k_dl3<<<(162 * HW + 255) / 256, 256, 0, stream>>>(L3, b_bbox, dl3);
    k_feat2<<<(512 * HW) / 256, 256, 0, stream>>>(conv1, feat2);
    k_gemm2d<<<(54 * HW) / 256, 256, 0, stream>>>(feat2, W_cls16, W_bbox16, L2);
    k_sc2<<<(9 * HW + 255) / 256, 256, 0, stream>>>(L2, b_cls16, sc2);
    k_dl2<<<(36 * HW + 255) / 256, 256, 0, stream>>>(L2, b_bbox16, dl2);
    k_proposal<<<2, 1024, 0, stream>>>(im_info, sc3, dl3, sc2, dl2, out);
}

// Round 7
// 1119.020 us; speedup vs baseline: 1.6858x; 1.6659x over previous
//
#include <hip/hip_runtime.h>
#include <hip/hip_bf16.h>
#include <cfloat>
#include <cstdint>

// ---------------------------------------------------------------------------
// RPN pipeline (B=1): conv3d(256->512,3x3x3,SAME)+ReLU -> heads -> proposals
// Shapes: base_feat (1,256,16,32,32), H=W=32, T=16
// Outputs: rois (1,128,7), rois16 (1,128,5), 4 scalar zeros -> 1540 floats
//
// Round-7: conv via MFMA bf16 with 3-way split / 6 products (fp32-equivalent
// precision: split residual 2^-27, dropped cross terms 2^-25 ~= fp32 mult
// rounding). fp32 VALU path plateaued at 1490-1590us (~50% of 737us FMA
// floor) across rounds 4-6.
// ---------------------------------------------------------------------------

#define T_DIM 16
#define H_DIM 32
#define W_DIM 32
#define NVOX  (T_DIM*H_DIM*W_DIM)   // 16384
#define HW    (H_DIM*W_DIM)         // 1024
#define CIN   256
#define COUT  512
#define PRE_NMS 1000
#define POST_NMS 128
#define NMS_TH 0.7f

typedef __attribute__((ext_vector_type(8))) short v8s;
typedef __attribute__((ext_vector_type(4))) float v4f;
typedef __attribute__((ext_vector_type(4))) int v4i;

#define MFMA_B16(A,B,C) __builtin_amdgcn_mfma_f32_16x16x32_bf16(A,B,C,0,0,0)

// bf16 RNE convert + back
__device__ __forceinline__ short f2bf(float x) {
    unsigned u = __float_as_uint(x);
    u += 0x7FFFu + ((u >> 16) & 1u);
    return (short)(u >> 16);
}
__device__ __forceinline__ float bf2f(short s) {
    return __uint_as_float(((unsigned)(unsigned short)s) << 16);
}
__device__ __forceinline__ int pk(short a, short b) {
    return (int)((unsigned short)a | ((unsigned)(unsigned short)b << 16));
}

// anchor tables: ratios (0.5,1.0,2.0) -> (ws,hs) = (23,12),(16,16),(11,22); scales 4,8,16
__constant__ float c_ws[3] = {23.f, 16.f, 11.f};
__constant__ float c_hs[3] = {12.f, 16.f, 22.f};
__constant__ float c_sc[3] = {4.f, 8.f, 16.f};
__constant__ float c_depth[3] = {16.f, 8.f, 4.f};

// ---------------------------------------------------------------------------
// Weight split: A{0,1,2}[tap][o][c] bf16 3-way split of W[o][c][tap]
__global__ void k_split_w(const float* __restrict__ W, short* __restrict__ A0,
                          short* __restrict__ A1, short* __restrict__ A2) {
    int i = blockIdx.x * 256 + threadIdx.x;   // over 27*512*256 = 3538944
    int c = i & 255;
    int o = (i >> 8) & 511;
    int tap = i >> 17;
    float x = W[(o * 256 + c) * 27 + tap];
    short h = f2bf(x); float r = x - bf2f(h);
    short m = f2bf(r); float r2 = r - bf2f(m);
    short l = f2bf(r2);
    A0[i] = h; A1[i] = m; A2[i] = l;
}

// Wcomb[c][o'] : o'<54 = W_cls[o'][c]; 54..215 = W_bbox[o'-54][c]; 216..255 = 0
__global__ void k_build_wcomb(const float* __restrict__ Wcls, const float* __restrict__ Wbb,
                              float* __restrict__ Wc) {
    int i = blockIdx.x * 256 + threadIdx.x;   // over 512*256
    int o = i & 255;
    int c = i >> 8;
    float v = 0.f;
    if (o < 54) v = Wcls[o * 512 + c];
    else if (o < 216) v = Wbb[(o - 54) * 512 + c];
    Wc[i] = v;
}

// ---------------------------------------------------------------------------
// MFMA conv3d: O[o][v] = relu(bias[o] + sum_{tap,c} W*Ishift), 128x128 tile,
// 256 thr (4 waves), BK=32, single-buffer LDS 48KB, 216 stages, 2 barriers.
// Per wave: 2(o) x 8(v) 16x16 tiles x 6 products = 96 MFMA/stage.
// A pre-split bf16 (k_split_w); B split in-kernel from fp32 I.

// split 8 floats -> 3 packed v4i (8 bf16 each)
#define SP8(X0,X1,X2,X3,X4,X5,X6,X7, OH, OM, OL) {                            \
    short h0_=f2bf(X0), h1_=f2bf(X1), h2_=f2bf(X2), h3_=f2bf(X3);             \
    short h4_=f2bf(X4), h5_=f2bf(X5), h6_=f2bf(X6), h7_=f2bf(X7);             \
    float r0_=(X0)-bf2f(h0_), r1_=(X1)-bf2f(h1_), r2_=(X2)-bf2f(h2_);         \
    float r3_=(X3)-bf2f(h3_), r4_=(X4)-bf2f(h4_), r5_=(X5)-bf2f(h5_);         \
    float r6_=(X6)-bf2f(h6_), r7_=(X7)-bf2f(h7_);                             \
    short m0_=f2bf(r0_), m1_=f2bf(r1_), m2_=f2bf(r2_), m3_=f2bf(r3_);         \
    short m4_=f2bf(r4_), m5_=f2bf(r5_), m6_=f2bf(r6_), m7_=f2bf(r7_);         \
    short l0_=f2bf(r0_-bf2f(m0_)), l1_=f2bf(r1_-bf2f(m1_));                   \
    short l2_=f2bf(r2_-bf2f(m2_)), l3_=f2bf(r3_-bf2f(m3_));                   \
    short l4_=f2bf(r4_-bf2f(m4_)), l5_=f2bf(r5_-bf2f(m5_));                   \
    short l6_=f2bf(r6_-bf2f(m6_)), l7_=f2bf(r7_-bf2f(m7_));                   \
    OH = (v4i){pk(h0_,h1_), pk(h2_,h3_), pk(h4_,h5_), pk(h6_,h7_)};           \
    OM = (v4i){pk(m0_,m1_), pk(m2_,m3_), pk(m4_,m5_), pk(m6_,m7_)};           \
    OL = (v4i){pk(l0_,l1_), pk(l2_,l3_), pk(l4_,l5_), pk(l6_,l7_)};           \
}

#define CV_SHIFT(TAP) {                                                       \
    int kt_ = (TAP) / 9 - 1, kh_ = ((TAP) / 3) % 3 - 1, kw_ = (TAP) % 3 - 1;  \
    int tt_ = bt + kt_, hh_ = bh + kh_, ww_ = bw + kw_;                       \
    bVal = ((unsigned)tt_ < 16u) && ((unsigned)hh_ < 32u) && ((unsigned)ww_ < 32u); \
    bOff = (tt_ << 10) + (hh_ << 5) + ww_;                                    \
}

#define CV_LOAD_A(TAP, CK) {                                                  \
    size_t ao_ = ((size_t)((TAP) * 512 + o0 + sa_o) << 8) + (CK) + sa_kh * 16;\
    qa00 = *(const v4i*)(A0 + ao_); qa01 = *(const v4i*)(A0 + ao_ + 8);       \
    qa10 = *(const v4i*)(A1 + ao_); qa11 = *(const v4i*)(A1 + ao_ + 8);       \
    qa20 = *(const v4i*)(A2 + ao_); qa21 = *(const v4i*)(A2 + ao_ + 8);       \
}

#define CV_LOAD_B(CK) {                                                       \
    const float* ip_ = I + ((size_t)((CK) + sa_kh * 16) << 14) + bOff;        \
    float x0_  = bVal ? ip_[0]        : 0.f;                                  \
    float x1_  = bVal ? ip_[1 << 14]  : 0.f;                                  \
    float x2_  = bVal ? ip_[2 << 14]  : 0.f;                                  \
    float x3_  = bVal ? ip_[3 << 14]  : 0.f;                                  \
    float x4_  = bVal ? ip_[4 << 14]  : 0.f;                                  \
    float x5_  = bVal ? ip_[5 << 14]  : 0.f;                                  \
    float x6_  = bVal ? ip_[6 << 14]  : 0.f;                                  \
    float x7_  = bVal ? ip_[7 << 14]  : 0.f;                                  \
    float x8_  = bVal ? ip_[8 << 14]  : 0.f;                                  \
    float x9_  = bVal ? ip_[9 << 14]  : 0.f;                                  \
    float x10_ = bVal ? ip_[10 << 14] : 0.f;                                  \
    float x11_ = bVal ? ip_[11 << 14] : 0.f;                                  \
    float x12_ = bVal ? ip_[12 << 14] : 0.f;                                  \
    float x13_ = bVal ? ip_[13 << 14] : 0.f;                                  \
    float x14_ = bVal ? ip_[14 << 14] : 0.f;                                  \
    float x15_ = bVal ? ip_[15 << 14] : 0.f;                                  \
    SP8(x0_,x1_,x2_,x3_,x4_,x5_,x6_,x7_,   pbh0, pbm0, pbl0);                 \
    SP8(x8_,x9_,x10_,x11_,x12_,x13_,x14_,x15_, pbh1, pbm1, pbl1);             \
}

__global__ __launch_bounds__(256) void k_conv3d_mfma(
        const float* __restrict__ I, const short* __restrict__ A0,
        const short* __restrict__ A1, const short* __restrict__ A2,
        const float* __restrict__ bias, float* __restrict__ O) {
    // [arr][k-quad][row][8 bf16]: fragment = one aligned ds_read_b128
    __shared__ __align__(16) short Ash[3][4][128][8];   // 24 KB
    __shared__ __align__(16) short Bsh[3][4][128][8];   // 24 KB
    const int tid = threadIdx.x;
    const int o0 = blockIdx.y * 128;
    const int v0 = blockIdx.x * 128;
    const int lane = tid & 63, wv = tid >> 6;
    const int quad = lane >> 4, m16 = lane & 15;

    // staging: thread -> (row = tid>>1, k-half = tid&1)
    const int sa_o = tid >> 1, sa_kh = tid & 1;         // also used as B's v row
    const int vbase = v0 + sa_o;
    const int bt = vbase >> 10, bh = (vbase >> 5) & 31, bw = vbase & 31;

    v4f acc[2][8];
#pragma unroll
    for (int i = 0; i < 2; i++)
#pragma unroll
        for (int j = 0; j < 8; j++) acc[i][j] = (v4f){0.f, 0.f, 0.f, 0.f};

    int bOff, bVal;
    v4i qa00, qa01, qa10, qa11, qa20, qa21;
    v4i pbh0, pbh1, pbm0, pbm1, pbl0, pbl1;

    CV_SHIFT(0);
    CV_LOAD_A(0, 0);
    CV_LOAD_B(0);

    const int ar0 = wv * 32 + m16;       // A fragment rows for this wave
    const int ar1 = ar0 + 16;

    for (int s = 0; s < 216; ++s) {      // 27 taps * 8 ck-steps (BK=32)
        __syncthreads();                 // previous compute done
        *(v4i*)(&Ash[0][sa_kh * 2    ][sa_o][0]) = qa00;
        *(v4i*)(&Ash[0][sa_kh * 2 + 1][sa_o][0]) = qa01;
        *(v4i*)(&Ash[1][sa_kh * 2    ][sa_o][0]) = qa10;
        *(v4i*)(&Ash[1][sa_kh * 2 + 1][sa_o][0]) = qa11;
        *(v4i*)(&Ash[2][sa_kh * 2    ][sa_o][0]) = qa20;
        *(v4i*)(&Ash[2][sa_kh * 2 + 1][sa_o][0]) = qa21;
        *(v4i*)(&Bsh[0][sa_kh * 2    ][sa_o][0]) = pbh0;
        *(v4i*)(&Bsh[0][sa_kh * 2 + 1][sa_o][0]) = pbh1;
        *(v4i*)(&Bsh[1][sa_kh * 2    ][sa_o][0]) = pbm0;
        *(v4i*)(&Bsh[1][sa_kh * 2 + 1][sa_o][0]) = pbm1;
        *(v4i*)(&Bsh[2][sa_kh * 2    ][sa_o][0]) = pbl0;
        *(v4i*)(&Bsh[2][sa_kh * 2 + 1][sa_o][0]) = pbl1;
        __syncthreads();
        // prefetch next stage (global latency hidden by 96 MFMA below)
        {
            int s1 = s + 1;
            if (s1 < 216) {
                int tap1 = s1 >> 3, ck1 = (s1 & 7) << 5;
                if ((s1 & 7) == 0) CV_SHIFT(tap1);
                CV_LOAD_A(tap1, ck1);
                CV_LOAD_B(ck1);
            }
        }
        // compute: frags + 96 MFMA
        v8s ah0 = *(const v8s*)(&Ash[0][quad][ar0][0]);
        v8s ah1 = *(const v8s*)(&Ash[0][quad][ar1][0]);
        v8s am0 = *(const v8s*)(&Ash[1][quad][ar0][0]);
        v8s am1 = *(const v8s*)(&Ash[1][quad][ar1][0]);
        v8s al0 = *(const v8s*)(&Ash[2][quad][ar0][0]);
        v8s al1 = *(const v8s*)(&Ash[2][quad][ar1][0]);
#pragma unroll
        for (int vt = 0; vt < 8; ++vt) {
            int vr = vt * 16 + m16;
            v8s bb = *(const v8s*)(&Bsh[0][quad][vr][0]);
            v8s bm = *(const v8s*)(&Bsh[1][quad][vr][0]);
            v8s bl = *(const v8s*)(&Bsh[2][quad][vr][0]);
            v4f a0 = acc[0][vt];
            a0 = MFMA_B16(ah0, bb, a0);
            a0 = MFMA_B16(ah0, bm, a0);
            a0 = MFMA_B16(am0, bb, a0);
            a0 = MFMA_B16(ah0, bl, a0);
            a0 = MFMA_B16(am0, bm, a0);
            a0 = MFMA_B16(al0, bb, a0);
            acc[0][vt] = a0;
            v4f a1 = acc[1][vt];
            a1 = MFMA_B16(ah1, bb, a1);
            a1 = MFMA_B16(ah1, bm, a1);
            a1 = MFMA_B16(am1, bb, a1);
            a1 = MFMA_B16(ah1, bl, a1);
            a1 = MFMA_B16(am1, bm, a1);
            a1 = MFMA_B16(al1, bb, a1);
            acc[1][vt] = a1;
        }
    }

    // epilogue: C/D layout col=lane&15 (v), row=quad*4+reg (o)
#pragma unroll
    for (int ot = 0; ot < 2; ++ot) {
#pragma unroll
        for (int r = 0; r < 4; ++r) {
            int o = o0 + wv * 32 + ot * 16 + quad * 4 + r;
            float bo = bias[o];
            float* dst = O + (size_t)o * NVOX + v0 + m16;
#pragma unroll
            for (int vt = 0; vt < 8; ++vt)
                dst[vt * 16] = fmaxf(acc[ot][vt][r] + bo, 0.f);
        }
    }
}

// ---------------------------------------------------------------------------
// logits3 GEMM: L[o][v] = sum_c Wc[c][o] * conv1[c][v], M=256 (padded), K=512, N=16384
// split-4 fragment layout (conflict-free LDS)
__global__ __launch_bounds__(256) void k_gemm_logits3(const float* __restrict__ conv1,
                                                      const float* __restrict__ Wc,
                                                      float* __restrict__ L) {
    __shared__ float As[16][128];
    __shared__ float Bs[16][128];
    const int tid = threadIdx.x;
    const int o0 = blockIdx.y * 128;
    const int v0 = blockIdx.x * 128;
    const int ty = tid >> 4, tx = tid & 15;

    float acc[8][8];
#pragma unroll
    for (int i = 0; i < 8; i++)
#pragma unroll
        for (int j = 0; j < 8; j++) acc[i][j] = 0.f;

    for (int ck = 0; ck < 512; ck += 16) {
        __syncthreads();
#pragma unroll
        for (int r = 0; r < 2; ++r) {
            int f = tid + r * 256;
            int c_l = f >> 5, o4 = (f & 31) << 2;
            *(float4*)(&As[c_l][o4]) = *(const float4*)(Wc + ((size_t)(ck + c_l) << 8) + o0 + o4);
        }
#pragma unroll
        for (int r = 0; r < 2; ++r) {
            int f = tid + r * 256;
            int c_l = f >> 5, v4 = (f & 31) << 2;
            *(float4*)(&Bs[c_l][v4]) = *(const float4*)(conv1 + ((size_t)(ck + c_l) << 14) + v0 + v4);
        }
        __syncthreads();
#pragma unroll
        for (int k = 0; k < 16; ++k) {
            float a[8], b[8];
            *(float4*)(a)     = *(const float4*)(&As[k][ty * 4]);
            *(float4*)(a + 4) = *(const float4*)(&As[k][64 + ty * 4]);
            *(float4*)(b)     = *(const float4*)(&Bs[k][tx * 4]);
            *(float4*)(b + 4) = *(const float4*)(&Bs[k][64 + tx * 4]);
#pragma unroll
            for (int i = 0; i < 8; i++)
#pragma unroll
                for (int j = 0; j < 8; j++)
                    acc[i][j] = fmaf(a[i], b[j], acc[i][j]);
        }
    }
#pragma unroll
    for (int i = 0; i < 8; i++) {
        int orow = (i < 4) ? (ty * 4 + i) : (64 + ty * 4 + (i - 4));
        float* dst = L + (size_t)(o0 + orow) * NVOX + v0;
        *(float4*)(dst + tx * 4)      = *(const float4*)(&acc[i][0]);
        *(float4*)(dst + 64 + tx * 4) = *(const float4*)(&acc[i][4]);
    }
}

// ---------------------------------------------------------------------------
// sc3[hw*27+a] = mean_t softmax-fg of (L[a]+b[a], L[27+a]+b[27+a])
__global__ void k_sc3(const float* __restrict__ L, const float* __restrict__ b_cls,
                      float* __restrict__ sc3) {
    int i = blockIdx.x * 256 + threadIdx.x;   // 27648
    if (i >= 27 * HW) return;
    int a = i >> 10, hw = i & 1023;
    float b0 = b_cls[a], b1 = b_cls[27 + a];
    const float* L0 = L + (size_t)a * NVOX + hw;
    const float* L1 = L + (size_t)(27 + a) * NVOX + hw;
    float s = 0.f;
    for (int t = 0; t < T_DIM; t++) {
        float x0 = L0[t * HW] + b0, x1 = L1[t * HW] + b1;
        float m = fmaxf(x0, x1);
        float e0 = expf(x0 - m), e1 = expf(x1 - m);
        s += e1 / (e0 + e1);
    }
    sc3[hw * 27 + a] = s * (1.f / 16.f);
}

// dl3[(hw*27+a)*6+d] = mean_t L[54+a*6+d] + b_bbox[a*6+d]
__global__ void k_dl3(const float* __restrict__ L, const float* __restrict__ b_bbox,
                      float* __restrict__ dl3) {
    int i = blockIdx.x * 256 + threadIdx.x;   // 165888
    if (i >= 162 * HW) return;
    int ch = i >> 10, hw = i & 1023;
    const float* Lr = L + (size_t)(54 + ch) * NVOX + hw;
    float s = 0.f;
    for (int t = 0; t < T_DIM; t++) s += Lr[t * HW];
    s = s * (1.f / 16.f) + b_bbox[ch];
    int a = ch / 6, d = ch - a * 6;
    dl3[((size_t)hw * 27 + a) * 6 + d] = s;
}

// feat2[c*1024+hw] = mean_t conv1[c][t*1024+hw]
__global__ void k_feat2(const float* __restrict__ conv1, float* __restrict__ feat2) {
    int i = blockIdx.x * 256 + threadIdx.x;   // 524288
    int c = i >> 10, hw = i & 1023;
    const float* src = conv1 + (size_t)c * NVOX + hw;
    float s = 0.f;
    for (int t = 0; t < T_DIM; t++) s += src[t * HW];
    feat2[i] = s * (1.f / 16.f);
}

// L2[o*1024+hw] (o<54): rows 0..17 = W_cls16, 18..53 = W_bbox16 (no bias)
__global__ void k_gemm2d(const float* __restrict__ feat2, const float* __restrict__ Wcls16,
                         const float* __restrict__ Wbb16, float* __restrict__ L2) {
    int g = blockIdx.x * 256 + threadIdx.x;   // 55296
    int o = g >> 10, hw = g & 1023;
    const float* wrow = (o < 18) ? (Wcls16 + (size_t)o * 512) : (Wbb16 + (size_t)(o - 18) * 512);
    float s = 0.f;
    for (int c = 0; c < 512; c++) s = fmaf(wrow[c], feat2[(size_t)c * HW + hw], s);
    L2[(size_t)o * HW + hw] = s;
}

__global__ void k_sc2(const float* __restrict__ L2, const float* __restrict__ b_cls16,
                      float* __restrict__ sc2) {
    int i = blockIdx.x * 256 + threadIdx.x;   // 9216
    if (i >= 9 * HW) return;
    int a = i >> 10, hw = i & 1023;
    float x0 = L2[(size_t)a * HW + hw] + b_cls16[a];
    float x1 = L2[(size_t)(9 + a) * HW + hw] + b_cls16[9 + a];
    float m = fmaxf(x0, x1);
    float e0 = expf(x0 - m), e1 = expf(x1 - m);
    sc2[hw * 9 + a] = e1 / (e0 + e1);
}

__global__ void k_dl2(const float* __restrict__ L2, const float* __restrict__ b_bbox16,
                      float* __restrict__ dl2) {
    int i = blockIdx.x * 256 + threadIdx.x;   // 36864
    if (i >= 36 * HW) return;
    int ch = i >> 10, hw = i & 1023;
    float v = L2[(size_t)(18 + ch) * HW + hw] + b_bbox16[ch];
    int a = ch >> 2, d = ch & 3;
    dl2[((size_t)hw * 9 + a) * 4 + d] = v;
}

// ---------------------------------------------------------------------------
// monotone map: larger float -> larger unsigned
__device__ __forceinline__ unsigned mapf(float f) {
    unsigned u = __float_as_uint(f);
    return (u & 0x80000000u) ? ~u : (u | 0x80000000u);
}

// proposal: radix-select top-1000 -> bitonic sort -> decode+clip -> bitmask NMS
// blockIdx.x = 0: 3D branch (A=27, nd=3), 1: 2D branch (A=9, nd=2)
__global__ __launch_bounds__(1024) void k_proposal(const float* __restrict__ im_info,
                                                   const float* __restrict__ sc3,
                                                   const float* __restrict__ dl3,
                                                   const float* __restrict__ sc2,
                                                   const float* __restrict__ dl2,
                                                   float* __restrict__ out) {
    const int branch = blockIdx.x;
    const int tid = threadIdx.x;
    const int A = (branch == 0) ? 27 : 9;
    const int nd = (branch == 0) ? 3 : 2;
    const float* scores = (branch == 0) ? sc3 : sc2;
    const float* deltas = (branch == 0) ? dl3 : dl2;
    const int K = PRE_NMS;
    const int ept = A;                 // elements per thread; S = 1024*ept
    const int base = tid * ept;

    __shared__ unsigned hist[256];
    __shared__ unsigned long long keys[1024];
    __shared__ float bx[PRE_NMS][6];
    __shared__ int keep[POST_NMS];
    __shared__ unsigned wsum[16];
    __shared__ unsigned long long alive[16];
    __shared__ int sh_b, sh_next, bcast;

    // ================= radix-select: find mapped value of K-th largest ======
    unsigned prefix = 0;
    int rank = K;                      // rank of target within current subset
    for (int shift = 24; shift >= 0; shift -= 8) {
        if (tid < 256) hist[tid] = 0;
        __syncthreads();
        const unsigned mask_hi = (shift == 24) ? 0u : (0xFFFFFFFFu << (shift + 8));
        for (int j = 0; j < ept; j++) {
            unsigned m = mapf(scores[base + j]);
            if ((m & mask_hi) == prefix)
                atomicAdd(&hist[(m >> shift) & 255], 1u);
        }
        __syncthreads();
        // suffix sums in place: hist[b] := sum_{j>=b} hist[j]
        for (int d = 1; d < 256; d <<= 1) {
            unsigned add = 0;
            if (tid < 256 && tid + d < 256) add = hist[tid + d];
            __syncthreads();
            if (tid < 256) hist[tid] += add;
            __syncthreads();
        }
        // b = max { b : suf[b] >= rank }  (unique winner writes)
        if (tid < 256) {
            bool win = (hist[tid] >= (unsigned)rank) &&
                       (tid == 255 || hist[tid + 1] < (unsigned)rank);
            if (win) { sh_b = tid; sh_next = (tid == 255) ? 0 : (int)hist[tid + 1]; }
        }
        __syncthreads();
        prefix |= (unsigned)sh_b << shift;
        rank -= sh_next;
        __syncthreads();
    }
    const unsigned tau = prefix;       // mapped K-th largest; rank = #eq needed

    // ================= compaction: >tau all, ==tau smallest-index 'rank' ====
    int gt_c = 0, eq_c = 0;
    for (int j = 0; j < ept; j++) {
        unsigned m = mapf(scores[base + j]);
        gt_c += (m > tau);
        eq_c += (m == tau);
    }
    unsigned cnt = ((unsigned)gt_c << 16) | (unsigned)eq_c;
    // block exclusive scan (index order)
    const int lane = tid & 63, wid = tid >> 6;
    unsigned x = cnt;
    for (int d = 1; d < 64; d <<= 1) {
        unsigned y = __shfl_up(x, d);
        if (lane >= d) x += y;
    }
    if (lane == 63) wsum[wid] = x;
    __syncthreads();
    if (wid == 0) {
        unsigned w = (lane < 16) ? wsum[lane] : 0;
        for (int d = 1; d < 16; d <<= 1) {
            unsigned y = __shfl_up(w, d);
            if (lane >= d) w += y;
        }
        if (lane < 16) wsum[lane] = w;
    }
    __syncthreads();
    unsigned excl = x - cnt + (wid ? wsum[wid - 1] : 0);
    const int c1 = (int)(wsum[15] >> 16);          // total count > tau (< K)
    int gi = (int)(excl >> 16);
    int ei = (int)(excl & 0xFFFFu);
    for (int j = 0; j < ept; j++) {
        int idx = base + j;
        unsigned m = mapf(scores[idx]);
        unsigned long long key = ((unsigned long long)m << 32) |
                                 (unsigned)(0xFFFFFFFFu - (unsigned)idx);
        if (m > tau) {
            keys[gi++] = key;
        } else if (m == tau) {
            if (c1 + ei < K) keys[c1 + ei] = key;
            ei++;
        }
    }
    if (tid < 1024 - K) keys[K + tid] = 0;         // pad tail
    __syncthreads();

    // ================= bitonic sort 1024 u64 keys, descending ===============
    for (int k = 2; k <= 1024; k <<= 1) {
        for (int j = k >> 1; j > 0; j >>= 1) {
            int ixj = tid ^ j;
            if (ixj > tid) {
                unsigned long long a = keys[tid], b = keys[ixj];
                bool sw = ((tid & k) == 0) ? (a < b) : (a > b);
                if (sw) { keys[tid] = b; keys[ixj] = a; }
            }
            __syncthreads();
        }
    }

    // ================= decode + clip ========================================
    const float imh = im_info[0], imw = im_info[1];
    if (tid < K) {
        int n = (int)(0xFFFFFFFFu - (unsigned)(keys[tid] & 0xFFFFFFFFull));
        int cell = n / A, a = n - cell * A;
        int hc = cell >> 5, wc = cell & 31;
        int a2 = (branch == 0) ? (a % 9) : a;
        int ri = a2 / 3, si = a2 % 3;
        float w = c_ws[ri] * c_sc[si], h = c_hs[ri] * c_sc[si];
        float lo[3], hi[3], mx[3];
        lo[0] = 7.5f - (w - 1.f) * 0.5f + 16.f * wc;
        hi[0] = 7.5f + (w - 1.f) * 0.5f + 16.f * wc;
        mx[0] = imw - 1.f;
        lo[1] = 7.5f - (h - 1.f) * 0.5f + 16.f * hc;
        hi[1] = 7.5f + (h - 1.f) * 0.5f + 16.f * hc;
        mx[1] = imh - 1.f;
        if (branch == 0) { lo[2] = 0.f; hi[2] = c_depth[a / 9] - 1.f; mx[2] = (float)(T_DIM - 1); }
        const float* dp = deltas + (size_t)n * (2 * nd);
        for (int d = 0; d < nd; d++) {
            float size = hi[d] - lo[d] + 1.f;
            float ctr = lo[d] + 0.5f * (size - 1.f);
            float pctr = dp[d] * size + ctr;
            float psize = expf(dp[nd + d]) * size;
            float pl = pctr - 0.5f * (psize - 1.f);
            float ph = pctr + 0.5f * (psize - 1.f);
            bx[tid][d]      = fminf(fmaxf(pl, 0.f), mx[d]);
            bx[tid][nd + d] = fminf(fmaxf(ph, 0.f), mx[d]);
        }
    }
    // init alive bitmask (bits 0..K-1 set)
    if (tid < 16) alive[tid] = (tid < 15) ? ~0ull : ((1ull << (K - 15 * 64)) - 1);
    __syncthreads();

    // ================= NMS (bitmask) ========================================
    float myb[6]; float myvol = 1.f;
    if (tid < K) {
        for (int d = 0; d < 6; d++) myb[d] = bx[tid][d];
        for (int d = 0; d < nd; d++) myvol *= (myb[nd + d] - myb[d] + 1.f);
    }
    for (int i = 0; i < POST_NMS; ++i) {
        if (tid < 64) {
            unsigned long long wv = (tid < 16) ? alive[tid] : 0ull;
            int cand = wv ? (tid * 64 + __ffsll(wv) - 1) : 0x7fffffff;
#pragma unroll
            for (int off = 32; off; off >>= 1)
                cand = min(cand, __shfl_xor(cand, off));
            if (tid == 0) {
                int m = (cand == 0x7fffffff) ? 0 : cand;
                bcast = m; keep[i] = m;
            }
        }
        __syncthreads();
        int sel = bcast;
        bool s = false;
        if (tid < K) {
            float inter = 1.f, selvol = 1.f;
            for (int d = 0; d < nd; d++) {
                float slo = bx[sel][d], shi = bx[sel][nd + d];
                float l = fmaxf(slo, myb[d]);
                float hh = fminf(shi, myb[nd + d]);
                inter *= fmaxf(hh - l + 1.f, 0.f);
                selvol *= (shi - slo + 1.f);
            }
            float iou = inter / (selvol + myvol - inter);
            s = (iou > NMS_TH) || (tid == sel);
        }
        unsigned long long bal = __ballot(s);
        if (lane == 0 && bal) alive[wid] &= ~bal;
        __syncthreads();
    }

    // ================= write outputs ========================================
    if (tid < POST_NMS) {
        int k = keep[tid];
        if (branch == 0) {
            float* o = out + (size_t)tid * 7;
            o[0] = 0.f;
            for (int d = 0; d < 6; d++) o[1 + d] = bx[k][d];
        } else {
            float* o = out + 128 * 7 + (size_t)tid * 5;
            o[0] = 0.f;
            for (int d = 0; d < 4; d++) o[1 + d] = bx[k][d];
        }
    }
    if (branch == 0 && tid == 0) {
        out[1536] = 0.f; out[1537] = 0.f; out[1538] = 0.f; out[1539] = 0.f;
    }
}

// ---------------------------------------------------------------------------
extern "C" void kernel_launch(void* const* d_in, const int* in_sizes, int n_in,
                              void* d_out, int out_size, void* d_ws, size_t ws_size,
                              hipStream_t stream) {
    (void)in_sizes; (void)n_in; (void)out_size; (void)ws_size;
    const float* base_feat = (const float*)d_in[0];
    const float* im_info   = (const float*)d_in[1];
    const float* W_conv    = (const float*)d_in[4];
    const float* b_conv    = (const float*)d_in[5];
    const float* W_cls     = (const float*)d_in[6];
    const float* b_cls     = (const float*)d_in[7];
    const float* W_bbox    = (const float*)d_in[8];
    const float* b_bbox    = (const float*)d_in[9];
    const float* W_cls16   = (const float*)d_in[10];
    const float* b_cls16   = (const float*)d_in[11];
    const float* W_bbox16  = (const float*)d_in[12];
    const float* b_bbox16  = (const float*)d_in[13];
    float* out = (float*)d_out;

    // workspace layout. Region 0 is time-shared: A0/A1/A2 (bf16 weight splits,
    // 21.2 MB, dead after conv) alias L3 (16.8 MB, written after conv).
    char* ws = (char*)d_ws;
    const size_t AW = (size_t)27 * 512 * 256;          // 3538944 shorts per array
    short* A0 = (short*)ws;
    short* A1 = A0 + AW;
    short* A2 = A1 + AW;
    float* L3 = (float*)ws;                            // alias (safe: sequential)
    size_t off = AW * 3 * sizeof(short);               // 21233664
    float* Wcomb  = (float*)(ws + off); off += (size_t)512 * 256 * 4;
    float* conv1  = (float*)(ws + off); off += (size_t)COUT * NVOX * 4;
    float* feat2  = (float*)(ws + off); off += (size_t)512 * HW * 4;
    float* L2     = (float*)(ws + off); off += (size_t)64 * HW * 4;
    float* sc3    = (float*)(ws + off); off += (size_t)27 * HW * 4;
    float* dl3    = (float*)(ws + off); off += (size_t)27 * HW * 6 * 4;
    float* sc2    = (float*)(ws + off); off += (size_t)9 * HW * 4;
    float* dl2    = (float*)(ws + off); off += (size_t)9 * HW * 4 * 4;

    k_split_w<<<13824, 256, 0, stream>>>(W_conv, A0, A1, A2);
    k_build_wcomb<<<512, 256, 0, stream>>>(W_cls, W_bbox, Wcomb);
    {
        dim3 g(NVOX / 128, COUT / 128);
        k_conv3d_mfma<<<g, 256, 0, stream>>>(base_feat, A0, A1, A2, b_conv, conv1);
    }
    {
        dim3 g(NVOX / 128, 2);
        k_gemm_logits3<<<g, 256, 0, stream>>>(conv1, Wcomb, L3);
    }
    k_sc3<<<(27 * HW + 255) / 256, 256, 0, stream>>>(L3, b_cls, sc3);
    k_dl3<<<(162 * HW + 255) / 256, 256, 0, stream>>>(L3, b_bbox, dl3);
    k_feat2<<<(512 * HW) / 256, 256, 0, stream>>>(conv1, feat2);
    k_gemm2d<<<(54 * HW) / 256, 256, 0, stream>>>(feat2, W_cls16, W_bbox16, L2);
    k_sc2<<<(9 * HW + 255) / 256, 256, 0, stream>>>(L2, b_cls16, sc2);
    k_dl2<<<(36 * HW + 255) / 256, 256, 0, stream>>>(L2, b_bbox16, dl2);
    k_proposal<<<2, 1024, 0, stream>>>(im_info, sc3, dl3, sc2, dl2, out);
}